// Round 10
// baseline (26287.509 us; speedup 1.0000x reference)
//
#include <hip/hip_runtime.h>

#define T_STEPS 32768
#define OUT_BASE 9830400  // 32768*300
#define RMASK 16383       // z1 ring = 16384 ticks (26.2 MB, in out-scratch)

typedef _Float16 h2 __attribute__((ext_vector_type(2)));
#define H2BC(f_) __builtin_bit_cast(h2, f_)

// relaxed/release agent-scope atomics (round-5/8/9-proven cross-XCD protocol)
#define ALD(p)     __hip_atomic_load((p), __ATOMIC_RELAXED, __HIP_MEMORY_SCOPE_AGENT)
#define AST(p, v)  __hip_atomic_store((p), (v), __ATOMIC_RELAXED, __HIP_MEMORY_SCOPE_AGENT)
#define ASTR(p, v) __hip_atomic_store((p), (v), __ATOMIC_RELEASE, __HIP_MEMORY_SCOPE_AGENT)
#define CFENCE()   asm volatile("" ::: "memory")

__device__ __forceinline__ float fdot2(h2 a, h2 b, float c) {
#if __has_builtin(__builtin_amdgcn_fdot2)
    return __builtin_amdgcn_fdot2(a, b, c, false);
#else
    return c + (float)a.x * (float)b.x + (float)a.y * (float)b.y;
#endif
}

__device__ __forceinline__ float sigf(float x) { return 1.f / (1.f + __expf(-x)); }

__device__ __forceinline__ float tanh_f(float x) {
    float a = fabsf(x);
    float e = __expf(-2.f * a);
    float t = (1.f - e) / (1.f + e);
    return x < 0.f ? -t : t;
}

// DPP cross-lane read. CTRL: 0xB1=quad xor1, 0x4E=quad xor2, 0x1B=quad xor3,
// 0x141=row_half_mirror (lane i <- lane 7-i within each 8-lane group).
// The 8-lane gather set {own, 0x4E, 0x141, 0x141∘0x1B} was validated bit-exact
// in round 3 (passed, absmax 0.001953125).
template <int CTRL>
__device__ __forceinline__ float qperm(float x) {
#if __has_builtin(__builtin_amdgcn_update_dpp)
    return __builtin_bit_cast(
        float, __builtin_amdgcn_update_dpp(0, __builtin_bit_cast(int, x), CTRL, 0xF, 0xF, true));
#else
    return __shfl_xor(x, CTRL == 0xB1 ? 1 : (CTRL == 0x4E ? 2 : (CTRL == 0x1B ? 3 : 7)));
#endif
}

// LDS-only barrier: keep global loads/stores (vmcnt) in flight across ticks.
__device__ __forceinline__ void bar_lds() {
    asm volatile("s_waitcnt lgkmcnt(0)\n\ts_barrier" ::: "memory");
}

// load 25 f16-pairs of one row-half (50 consecutive floats) into h2 regs
__device__ __forceinline__ void ldw(h2* w, const float* p) {
#pragma unroll
    for (int k = 0; k < 25; k++) {
        float2 v = ((const float2*)p)[k];
        h2 t; t.x = (_Float16)v.x; t.y = (_Float16)v.y; w[k] = t;
    }
}

// single-row half MV: 25 h2 against rec half (6 x b128 + 1 x b32, 16B-aligned),
// TWO accumulator chains (depth 13) to halve the dependent-latency chain.
__device__ __forceinline__ float mv25s(const h2* w, const char* rec) {
    const float4* hv = (const float4*)rec;
    float a0 = 0.f, a1 = 0.f;
#pragma unroll
    for (int c = 0; c < 6; c++) {
        float4 v = hv[c];
        a0 = fdot2(w[4 * c + 0], H2BC(v.x), a0);
        a1 = fdot2(w[4 * c + 1], H2BC(v.y), a1);
        a0 = fdot2(w[4 * c + 2], H2BC(v.z), a0);
        a1 = fdot2(w[4 * c + 3], H2BC(v.w), a1);
    }
    float vl = *(const float*)(rec + 96);
    a0 = fdot2(w[24], H2BC(vl), a0);
    return a0 + a1;
}

// ---------------- A0: Wc = W_ih_l0 @ W_inp  [400x300]; bc = W_ih_l0@b_inp + b_ih0 + b_hh0 ----------------
__global__ void k_precomp(const float* __restrict__ W_inp, const float* __restrict__ b_inp,
                          const float* __restrict__ W_ih0, const float* __restrict__ b_ih0,
                          const float* __restrict__ b_hh0,
                          float* __restrict__ Wc, float* __restrict__ bc) {
    int idx = blockIdx.x * 256 + threadIdx.x;
    if (idx < 120000) {
        int r = idx / 300, d = idx % 300;
        float acc = 0.f;
        for (int h = 0; h < 100; h++) acc += W_ih0[r * 100 + h] * W_inp[h * 300 + d];
        Wc[idx] = acc;
    } else if (idx < 120400) {
        int r = idx - 120000;
        float acc = b_ih0[r] + b_hh0[r];
        for (int h = 0; h < 100; h++) acc += W_ih0[r * 100 + h] * b_inp[h];
        bc[r] = acc;
    }
}

// ---------------- A1: x0p[t][u*4+g] = inputs[t] . Wc[g*100+u] + bc, stored f16 ----------------
__global__ __launch_bounds__(512) void k_xproj(const float* __restrict__ inp,
                                               const float* __restrict__ Wc,
                                               const float* __restrict__ bc,
                                               _Float16* __restrict__ x0p) {
    __shared__ float xs[32 * 300];
    int t0 = blockIdx.x * 32;
    for (int idx = threadIdx.x; idx < 9600; idx += 512) xs[idx] = inp[(size_t)t0 * 300 + idx];
    __syncthreads();
    int j = threadIdx.x;
    if (j < 400) {
        float acc[32];
#pragma unroll
        for (int i = 0; i < 32; i++) acc[i] = 0.f;
        const float4* w4 = (const float4*)(Wc + j * 300);
        const float4* x4 = (const float4*)xs;
        for (int d4 = 0; d4 < 75; d4++) {
            float4 w = w4[d4];
#pragma unroll
            for (int ti = 0; ti < 32; ti++) {
                float4 x = x4[ti * 75 + d4];
                acc[ti] += w.x * x.x + w.y * x.y + w.z * x.z + w.w * x.w;
            }
        }
        float bb = bc[j];
        int dst = (j % 100) * 4 + j / 100;
#pragma unroll
        for (int ti = 0; ti < 32; ti++)
            x0p[(size_t)(t0 + ti) * 400 + dst] = (_Float16)(acc[ti] + bb);
    }
}

// ================= Three-CU pipelined scan, 1-row half-split =================
// grid=3 cooperative, block 896 (14 waves, {4,4,3,3}/SIMD). Lane j<800: pair
// p=j>>1 (row r = q*100+u, q=(j>>1)&3, u=j>>3), half H=j&1 (cols 50H..50H+49).
// Per-lane: 25 h2 weights, 26 fdot2 in 2 chains of 13 -> demand ~50 VGPR, fits
// the 64-VGPR floor the allocator picks for big blocks (rounds 2-4 pathology
// defused by design). 1.75x TLP vs round 9's 2-wave/SIMD shape = latency hiding
// for the serial recurrence chain (the round-9 limiter).
// After mv25s, s += dpp_xor1(s) combines halves (both lanes of pair get full
// row sum); gather on 8-lane unit-group leader (j&7==0): i=own, f=xor2(lane2),
// o=mirror(lane7), g=mirror∘xor3(lane4). Helper wave = lanes 832..895 (own
// vmcnt domain). Protocol/flags/ring: round-9 verbatim.
// flags[]: [0]=h0 progress  [1]=z tiles done  [2]=B2 progress (backpressure)

#define B0TICK(T_, XR_, P_) do {                                                             \
    if (j < 800) {                                                                           \
        float xc_ = XR_;                                                                     \
        int tn_ = (T_) + 2 < T_STEPS ? (T_) + 2 : T_STEPS - 1;                               \
        XR_ = (float)x0p[(size_t)tn_ * 400 + (j >> 1)];                                      \
        float s_v = mv25s(w, (const char*)(lds + (P_) * 112) + hoff);                        \
        s_v += qperm<0xB1>(s_v);                                                             \
        s_v += xc_;                                                                          \
        float nl_ = __builtin_fmaf(sigf(s_v * s_), s_, addc_);                               \
        float fg_ = qperm<0x4E>(nl_);                                                        \
        float og_ = qperm<0x141>(nl_);                                                       \
        float gg_ = qperm<0x141>(qperm<0x1B>(nl_));                                          \
        if ((j & 7) == 0) {                                                                  \
            c0 = fg_ * c0 + nl_ * gg_;                                                       \
            float h0v_ = og_ * tanh_f(c0);                                                   \
            ((_Float16*)(lds + (1 - (P_)) * 112))[hidx] = (_Float16)h0v_;                    \
            if ((T_) == T_STEPS - 1) { outTail[u] = h0v_; outTail[200 + u] = c0; }           \
        }                                                                                    \
    } else if (j >= 832) {                                                                   \
        if (kk < 50 && (T_) >= 1)                                                            \
            AST(&h0seq[(size_t)((T_) - 1) * 50 + kk], (lds + (P_) * 112)[pidx]);             \
        if (kk == 0 && (((T_) & 7) == 7)) ASTR(&flags[0], (unsigned)(T_));                   \
    }                                                                                        \
    bar_lds();                                                                               \
} while (0)

#define B2TICK(T_, ZR_, P_) do {                                                             \
    if (j < 800) {                                                                           \
        float zc_ = ZR_;                                                                     \
        int tn_ = (T_) + 2 < T_STEPS ? (T_) + 2 : T_STEPS - 1;                               \
        ZR_ = ALD(&z1ring[(size_t)(tn_ & RMASK) * 400 + (j >> 1)]);                          \
        float s_v = mv25s(w, (const char*)(lds + (P_) * 112) + hoff);                        \
        s_v += qperm<0xB1>(s_v);                                                             \
        s_v += zc_; /* z1 already includes b_ih1+b_hh1 */                                    \
        float nl_ = __builtin_fmaf(sigf(s_v * s_), s_, addc_);                               \
        float fg_ = qperm<0x4E>(nl_);                                                        \
        float og_ = qperm<0x141>(nl_);                                                       \
        float gg_ = qperm<0x141>(qperm<0x1B>(nl_));                                          \
        if ((j & 7) == 0) {                                                                  \
            c1 = fg_ * c1 + nl_ * gg_;                                                       \
            float h1v_ = og_ * tanh_f(c1);                                                   \
            ((_Float16*)(lds + (1 - (P_)) * 112))[hidx] = (_Float16)h1v_;                    \
            h1s[(size_t)(T_) * 100 + u] = h1v_;                                              \
            if ((T_) == T_STEPS - 1) { outTail[100 + u] = h1v_; outTail[300 + u] = c1; }     \
        }                                                                                    \
    } else if (j == 832) {                                                                   \
        int tq_ = (T_) + 3 < T_STEPS ? (T_) + 3 : T_STEPS - 1;                               \
        unsigned need_ = (unsigned)(tq_ >> 4) + 1u;                                          \
        if (zdc < need_) {                                                                   \
            while ((zdc = ALD(&flags[1])) < need_) __builtin_amdgcn_s_sleep(2);              \
            CFENCE();                                                                        \
        }                                                                                    \
        if (((T_) & 255) == 255) ASTR(&flags[2], (unsigned)(T_) + 1u);                       \
    }                                                                                        \
    bar_lds();                                                                               \
} while (0)

__global__ __launch_bounds__(896)
void k_scan3(const _Float16* __restrict__ x0p,
             const float* __restrict__ Whh0,
             const float* __restrict__ Wih1,
             const float* __restrict__ Whh1,
             const float* __restrict__ bih1,
             const float* __restrict__ bhh1,
             float* __restrict__ h1s,
             float* __restrict__ outTail,
             unsigned* __restrict__ h0seq,
             float* __restrict__ z1ring,
             unsigned* __restrict__ flags) {
    // B0/B2: double-buffered record at lds[P*112 .. P*112+55]. Bz: 16 records.
    __shared__ __align__(16) unsigned lds[16 * 56];
    const int j = threadIdx.x;
    const int q = (j >> 1) & 3, u = j >> 3, H = j & 1;
    const int hoff = H * 112;                       // byte offset of my half in a record
    const int hidx = (u < 50) ? u : 56 + (u - 50);  // f16 index of h[u] in padded record
    const int kk = j - 832;
    const int pidx = (kk < 25) ? kk : kk + 3;       // u32 index of packed pair kk
    const float s_ = (q == 2) ? 2.f : 1.f;          // lane q==2: tanh = 2*sig(2x)-1
    const float addc_ = (q == 2) ? -1.f : 0.f;

    if (blockIdx.x == 0) {
        // ---------------- B0: layer-0 scan ----------------
        h2 w[25];
        float xa = 0.f, xb = 0.f, c0 = 0.f;
        if (j < 800) {
            int r = q * 100 + u;
            ldw(w, Whh0 + r * 100 + 50 * H);
            xa = (float)x0p[j >> 1];          // x(0), permuted layout
            xb = (float)x0p[400 + (j >> 1)];  // x(1)
        }
        if (j < 224) lds[j] = 0u;  // h0(-1)=0, both buffers
        __syncthreads();

        for (int t = 0; t < T_STEPS; t += 2) {
            B0TICK(t, xa, 0);
            B0TICK(t + 1, xb, 1);
        }
        if (j >= 832) {  // publish h0(T-1) (sits in buffer 0) + final flag
            if (kk < 50) AST(&h0seq[(size_t)(T_STEPS - 1) * 50 + kk], lds[pidx]);
            if (kk == 0) ASTR(&flags[0], (unsigned)T_STEPS);
        }
    } else if (blockIdx.x == 1) {
        // ---------------- Bz: z1 streaming GEMM, 16-tick tiles ----------------
        h2 w[25];
        float bz = 0.f;
        if (j < 800) {
            int r = q * 100 + u;
            ldw(w, Wih1 + r * 100 + 50 * H);
            bz = bih1[r] + bhh1[r];
        }
        for (int idx = j; idx < 16 * 56; idx += 896) lds[idx] = 0u;
        __syncthreads();

        unsigned fcache = 0, bpc = 0;
        for (int tau = 0; tau < 2048; ++tau) {
            const int t0 = tau * 16;
            // h0 availability: flags[0]=T means h0seq ticks <= T-1 done; need t0+15
            while (fcache < (unsigned)(t0 + 16)) {
                fcache = ALD(&flags[0]);
                if (fcache < (unsigned)(t0 + 16)) __builtin_amdgcn_s_sleep(8);
            }
            // ring backpressure (round-7 corruption fix): B2 must be within
            // 16384-32 ticks of the slots we are about to overwrite.
            int lim = t0 + 32 - (RMASK + 1);
            if (lim > 0) {
                while ((int)bpc < lim) {
                    bpc = ALD(&flags[2]);
                    if ((int)bpc < lim) __builtin_amdgcn_s_sleep(8);
                }
            }
            CFENCE();
            // stage tile: 800 packed u32 -> 16 padded LDS records
            if (j < 800) {
                int tt = j / 50, k = j % 50;
                lds[tt * 56 + ((k < 25) ? k : k + 3)] = ALD(&h0seq[(size_t)t0 * 50 + j]);
            }
            __syncthreads();
            if (j < 800) {
                for (int tt = 0; tt < 16; ++tt) {
                    float s_v = mv25s(w, (const char*)(lds + tt * 56) + hoff);
                    s_v += qperm<0xB1>(s_v);
                    if (H == 0)
                        AST(&z1ring[(size_t)((t0 + tt) & RMASK) * 400 + (j >> 1)], s_v + bz);
                }
            }
            __syncthreads();  // per-wave vmcnt(0) drain -> all z stores complete
            if (j == 0) ASTR(&flags[1], (unsigned)(tau + 1));
        }
    } else {
        // ---------------- B2: layer-1 scan ----------------
        h2 w[25];
        float za = 0.f, zb = 0.f, c1 = 0.f;
        unsigned zdc = 0;
        if (j < 800) {
            int r = q * 100 + u;
            ldw(w, Whh1 + r * 100 + 50 * H);
        }
        if (j < 224) lds[j] = 0u;  // h1(-1)=0, both buffers
        __syncthreads();
        if (j == 832) {  // wait for z tile 0 (ticks 0..15)
            while ((zdc = ALD(&flags[1])) < 1u) __builtin_amdgcn_s_sleep(8);
            CFENCE();
        }
        __syncthreads();
        if (j < 800) {
            za = ALD(&z1ring[j >> 1]);        // z(0)
            zb = ALD(&z1ring[400 + (j >> 1)]);  // z(1)
        }

        for (int t = 0; t < T_STEPS; t += 2) {
            B2TICK(t, za, 0);      // use z(t); prefetch za=z(t+2)
            B2TICK(t + 1, zb, 1);  // use z(t+1); prefetch zb=z(t+3)
        }
    }
}

// ---------------- C: outputs[t][d] = h1s[t] . W_out[d] + b_out[d] ----------------
__global__ __launch_bounds__(320) void k_out(const float* __restrict__ h1s,
                                             const float* __restrict__ Wout,
                                             const float* __restrict__ bout,
                                             float* __restrict__ out) {
    __shared__ float hs[32 * 100];
    int t0 = blockIdx.x * 32;
    for (int idx = threadIdx.x; idx < 3200; idx += 320) hs[idx] = h1s[(size_t)t0 * 100 + idx];
    __syncthreads();
    int d = threadIdx.x;
    if (d < 300) {
        float acc[32];
#pragma unroll
        for (int i = 0; i < 32; i++) acc[i] = 0.f;
        const float4* w4 = (const float4*)(Wout + d * 100);
        const float4* h4 = (const float4*)hs;
        for (int j4 = 0; j4 < 25; j4++) {
            float4 w = w4[j4];
#pragma unroll
            for (int ti = 0; ti < 32; ti++) {
                float4 h = h4[ti * 25 + j4];
                acc[ti] += w.x * h.x + w.y * h.y + w.z * h.z + w.w * h.w;
            }
        }
        float bb = bout[d];
#pragma unroll
        for (int ti = 0; ti < 32; ti++) out[(size_t)(t0 + ti) * 300 + d] = acc[ti] + bb;
    }
}

extern "C" void kernel_launch(void* const* d_in, const int* in_sizes, int n_in,
                              void* d_out, int out_size, void* d_ws, size_t ws_size,
                              hipStream_t stream) {
    const float* inputs = (const float*)d_in[0];
    const float* W_inp  = (const float*)d_in[1];
    const float* b_inp  = (const float*)d_in[2];
    const float* W_ih0  = (const float*)d_in[3];
    const float* W_hh0  = (const float*)d_in[4];
    const float* b_ih0  = (const float*)d_in[5];
    const float* b_hh0  = (const float*)d_in[6];
    const float* W_ih1  = (const float*)d_in[7];
    const float* W_hh1  = (const float*)d_in[8];
    const float* b_ih1  = (const float*)d_in[9];
    const float* b_hh1  = (const float*)d_in[10];
    const float* W_out  = (const float*)d_in[11];
    const float* b_out  = (const float*)d_in[12];
    float* out = (float*)d_out;

    char* ws = (char*)d_ws;
    _Float16* x0p = (_Float16*)ws;                    // 32768*400*2 = 26,214,400 B
    float* h1s = (float*)(ws + 26214400);             // 32768*100*4 = 13,107,200 B
    float* Wc  = (float*)(ws + 26214400 + 13107200);  // 400*300*4   =    480,000 B
    float* bc  = Wc + 120000;                         // 400*4 B

    // out-scratch region [0, OUT_BASE*4): fully overwritten by k_out afterwards.
    //   z1ring: 16384*400*4 = 26,214,400 B  @ 0
    //   h0seq : 32768*50*4  =  6,553,600 B  @ 26,214,400
    //   flags : 3 u32                       @ 32,768,000   (all < 39,321,600)
    float*    z1ring = out;
    unsigned* h0seq  = (unsigned*)((char*)out + 26214400);
    unsigned* flagsp = (unsigned*)((char*)out + 32768000);
    float*    outTail = out + OUT_BASE;

    hipMemsetAsync(flagsp, 0, 16, stream);
    k_precomp<<<471, 256, 0, stream>>>(W_inp, b_inp, W_ih0, b_ih0, b_hh0, Wc, bc);
    k_xproj<<<1024, 512, 0, stream>>>(inputs, Wc, bc, x0p);

    void* args[] = {(void*)&x0p, (void*)&W_hh0, (void*)&W_ih1, (void*)&W_hh1,
                    (void*)&b_ih1, (void*)&b_hh1, (void*)&h1s, (void*)&outTail,
                    (void*)&h0seq, (void*)&z1ring, (void*)&flagsp};
    hipLaunchCooperativeKernel((void*)k_scan3, dim3(3), dim3(896), args, 0, stream);

    k_out<<<1024, 320, 0, stream>>>(h1s, W_out, b_out, out);
}

// Round 11
// 26093.176 us; speedup vs baseline: 1.0074x; 1.0074x over previous
//
#include <hip/hip_runtime.h>

#define T_STEPS 32768
#define OUT_BASE 9830400  // 32768*300
#define RMASK 16383       // z1 ring = 16384 ticks (26.2 MB, in out-scratch)

typedef _Float16 h2 __attribute__((ext_vector_type(2)));
#define H2BC(f_) __builtin_bit_cast(h2, f_)

// relaxed/release agent-scope atomics (round-5/8/9-proven cross-XCD protocol)
#define ALD(p)     __hip_atomic_load((p), __ATOMIC_RELAXED, __HIP_MEMORY_SCOPE_AGENT)
#define AST(p, v)  __hip_atomic_store((p), (v), __ATOMIC_RELAXED, __HIP_MEMORY_SCOPE_AGENT)
#define ASTR(p, v) __hip_atomic_store((p), (v), __ATOMIC_RELEASE, __HIP_MEMORY_SCOPE_AGENT)
#define CFENCE()   asm volatile("" ::: "memory")

__device__ __forceinline__ float fdot2(h2 a, h2 b, float c) {
#if __has_builtin(__builtin_amdgcn_fdot2)
    return __builtin_amdgcn_fdot2(a, b, c, false);
#else
    return c + (float)a.x * (float)b.x + (float)a.y * (float)b.y;
#endif
}

__device__ __forceinline__ float sigf(float x) { return 1.f / (1.f + __expf(-x)); }

__device__ __forceinline__ float tanh_f(float x) {
    float a = fabsf(x);
    float e = __expf(-2.f * a);
    float t = (1.f - e) / (1.f + e);
    return x < 0.f ? -t : t;
}

// DPP cross-lane read. CTRL: 0xB1=quad xor1, 0x4E=quad xor2, 0x1B=quad xor3,
// 0x141=row_half_mirror (lane i <- lane 7-i within each 8-lane group).
// The 8-lane gather set {own, 0x4E, 0x141, 0x141∘0x1B} was validated bit-exact
// in round 3 (passed, absmax 0.001953125) and re-validated in round 10.
template <int CTRL>
__device__ __forceinline__ float qperm(float x) {
#if __has_builtin(__builtin_amdgcn_update_dpp)
    return __builtin_bit_cast(
        float, __builtin_amdgcn_update_dpp(0, __builtin_bit_cast(int, x), CTRL, 0xF, 0xF, true));
#else
    return __shfl_xor(x, CTRL == 0xB1 ? 1 : (CTRL == 0x4E ? 2 : (CTRL == 0x1B ? 3 : 7)));
#endif
}

// LDS-only barrier: keep global loads/stores (vmcnt) in flight across ticks.
__device__ __forceinline__ void bar_lds() {
    asm volatile("s_waitcnt lgkmcnt(0)\n\ts_barrier" ::: "memory");
}

// load 25 f16-pairs of one row-half (50 consecutive floats) into h2 regs
__device__ __forceinline__ void ldw(h2* w, const float* p) {
#pragma unroll
    for (int k = 0; k < 25; k++) {
        float2 v = ((const float2*)p)[k];
        h2 t; t.x = (_Float16)v.x; t.y = (_Float16)v.y; w[k] = t;
    }
}

// single-row half MV: 25 h2 against rec half (6 x b128 + 1 x b32, 16B-aligned),
// TWO accumulator chains (depth 13) to halve the dependent-latency chain.
__device__ __forceinline__ float mv25s(const h2* w, const char* rec) {
    const float4* hv = (const float4*)rec;
    float a0 = 0.f, a1 = 0.f;
#pragma unroll
    for (int c = 0; c < 6; c++) {
        float4 v = hv[c];
        a0 = fdot2(w[4 * c + 0], H2BC(v.x), a0);
        a1 = fdot2(w[4 * c + 1], H2BC(v.y), a1);
        a0 = fdot2(w[4 * c + 2], H2BC(v.z), a0);
        a1 = fdot2(w[4 * c + 3], H2BC(v.w), a1);
    }
    float vl = *(const float*)(rec + 96);
    a0 = fdot2(w[24], H2BC(vl), a0);
    return a0 + a1;
}

// ---------------- A0: Wc = W_ih_l0 @ W_inp  [400x300]; bc = W_ih_l0@b_inp + b_ih0 + b_hh0 ----------------
__global__ void k_precomp(const float* __restrict__ W_inp, const float* __restrict__ b_inp,
                          const float* __restrict__ W_ih0, const float* __restrict__ b_ih0,
                          const float* __restrict__ b_hh0,
                          float* __restrict__ Wc, float* __restrict__ bc) {
    int idx = blockIdx.x * 256 + threadIdx.x;
    if (idx < 120000) {
        int r = idx / 300, d = idx % 300;
        float acc = 0.f;
        for (int h = 0; h < 100; h++) acc += W_ih0[r * 100 + h] * W_inp[h * 300 + d];
        Wc[idx] = acc;
    } else if (idx < 120400) {
        int r = idx - 120000;
        float acc = b_ih0[r] + b_hh0[r];
        for (int h = 0; h < 100; h++) acc += W_ih0[r * 100 + h] * b_inp[h];
        bc[r] = acc;
    }
}

// ---------------- A1: x0p[t][u*4+g] = inputs[t] . Wc[g*100+u] + bc, stored f16 ----------------
__global__ __launch_bounds__(512) void k_xproj(const float* __restrict__ inp,
                                               const float* __restrict__ Wc,
                                               const float* __restrict__ bc,
                                               _Float16* __restrict__ x0p) {
    __shared__ float xs[32 * 300];
    int t0 = blockIdx.x * 32;
    for (int idx = threadIdx.x; idx < 9600; idx += 512) xs[idx] = inp[(size_t)t0 * 300 + idx];
    __syncthreads();
    int j = threadIdx.x;
    if (j < 400) {
        float acc[32];
#pragma unroll
        for (int i = 0; i < 32; i++) acc[i] = 0.f;
        const float4* w4 = (const float4*)(Wc + j * 300);
        const float4* x4 = (const float4*)xs;
        for (int d4 = 0; d4 < 75; d4++) {
            float4 w = w4[d4];
#pragma unroll
            for (int ti = 0; ti < 32; ti++) {
                float4 x = x4[ti * 75 + d4];
                acc[ti] += w.x * x.x + w.y * x.y + w.z * x.z + w.w * x.w;
            }
        }
        float bb = bc[j];
        int dst = (j % 100) * 4 + j / 100;
#pragma unroll
        for (int ti = 0; ti < 32; ti++)
            x0p[(size_t)(t0 + ti) * 400 + dst] = (_Float16)(acc[ti] + bb);
    }
}

// ================= Three-CU pipelined scan, 1-row half-split =================
// grid=3 cooperative, block 896 (14 waves, {4,4,3,3}/SIMD). Lane j<800: pair
// p=j>>1 (row r = q*100+u, q=(j>>1)&3, u=j>>3), half H=j&1 (cols 50H..50H+49).
// Per-lane demand ~50 VGPR (25 h2 weights + temps).
//
// REGISTER PIN (the round-10 bug): plain __launch_bounds__(896) let the
// allocator pick VGPR_Count=36 < demand -> weight spills -> 26 ms. 
// amdgpu_waves_per_eu(4,4) pins the 128-slot budget with arch=64 (proven in
// round 3 on a 13-wave block: VGPR_Count=64); demand ~50 fits in 64 with zero
// spill, and 4 waves/SIMD is exactly what the {4,4,3,3} block shape needs.
//
// After mv25s, s += dpp_xor1(s) combines halves; gather on 8-lane unit-group
// leader (j&7==0): i=own, f=xor2(lane2), o=mirror(lane7), g=mirror∘xor3(lane4).
// Helper wave = lanes 832..895 (own vmcnt domain). Protocol/ring: round-9 verbatim.
// flags[]: [0]=h0 progress  [1]=z tiles done  [2]=B2 progress (backpressure)

#define B0TICK(T_, XR_, P_) do {                                                             \
    if (j < 800) {                                                                           \
        float xc_ = XR_;                                                                     \
        int tn_ = (T_) + 2 < T_STEPS ? (T_) + 2 : T_STEPS - 1;                               \
        XR_ = (float)x0p[(size_t)tn_ * 400 + (j >> 1)];                                      \
        float s_v = mv25s(w, (const char*)(lds + (P_) * 112) + hoff);                        \
        s_v += qperm<0xB1>(s_v);                                                             \
        s_v += xc_;                                                                          \
        float nl_ = __builtin_fmaf(sigf(s_v * s_), s_, addc_);                               \
        float fg_ = qperm<0x4E>(nl_);                                                        \
        float og_ = qperm<0x141>(nl_);                                                       \
        float gg_ = qperm<0x141>(qperm<0x1B>(nl_));                                          \
        if ((j & 7) == 0) {                                                                  \
            c0 = fg_ * c0 + nl_ * gg_;                                                       \
            float h0v_ = og_ * tanh_f(c0);                                                   \
            ((_Float16*)(lds + (1 - (P_)) * 112))[hidx] = (_Float16)h0v_;                    \
            if ((T_) == T_STEPS - 1) { outTail[u] = h0v_; outTail[200 + u] = c0; }           \
        }                                                                                    \
    } else if (j >= 832) {                                                                   \
        if (kk < 50 && (T_) >= 1)                                                            \
            AST(&h0seq[(size_t)((T_) - 1) * 50 + kk], (lds + (P_) * 112)[pidx]);             \
        if (kk == 0 && (((T_) & 7) == 7)) ASTR(&flags[0], (unsigned)(T_));                   \
    }                                                                                        \
    bar_lds();                                                                               \
} while (0)

#define B2TICK(T_, ZR_, P_) do {                                                             \
    if (j < 800) {                                                                           \
        float zc_ = ZR_;                                                                     \
        int tn_ = (T_) + 2 < T_STEPS ? (T_) + 2 : T_STEPS - 1;                               \
        ZR_ = ALD(&z1ring[(size_t)(tn_ & RMASK) * 400 + (j >> 1)]);                          \
        float s_v = mv25s(w, (const char*)(lds + (P_) * 112) + hoff);                        \
        s_v += qperm<0xB1>(s_v);                                                             \
        s_v += zc_; /* z1 already includes b_ih1+b_hh1 */                                    \
        float nl_ = __builtin_fmaf(sigf(s_v * s_), s_, addc_);                               \
        float fg_ = qperm<0x4E>(nl_);                                                        \
        float og_ = qperm<0x141>(nl_);                                                       \
        float gg_ = qperm<0x141>(qperm<0x1B>(nl_));                                          \
        if ((j & 7) == 0) {                                                                  \
            c1 = fg_ * c1 + nl_ * gg_;                                                       \
            float h1v_ = og_ * tanh_f(c1);                                                   \
            ((_Float16*)(lds + (1 - (P_)) * 112))[hidx] = (_Float16)h1v_;                    \
            h1s[(size_t)(T_) * 100 + u] = h1v_;                                              \
            if ((T_) == T_STEPS - 1) { outTail[100 + u] = h1v_; outTail[300 + u] = c1; }     \
        }                                                                                    \
    } else if (j == 832) {                                                                   \
        int tq_ = (T_) + 3 < T_STEPS ? (T_) + 3 : T_STEPS - 1;                               \
        unsigned need_ = (unsigned)(tq_ >> 4) + 1u;                                          \
        if (zdc < need_) {                                                                   \
            while ((zdc = ALD(&flags[1])) < need_) __builtin_amdgcn_s_sleep(2);              \
            CFENCE();                                                                        \
        }                                                                                    \
        if (((T_) & 255) == 255) ASTR(&flags[2], (unsigned)(T_) + 1u);                       \
    }                                                                                        \
    bar_lds();                                                                               \
} while (0)

__global__ __launch_bounds__(896) __attribute__((amdgpu_waves_per_eu(4, 4)))
void k_scan3(const _Float16* __restrict__ x0p,
             const float* __restrict__ Whh0,
             const float* __restrict__ Wih1,
             const float* __restrict__ Whh1,
             const float* __restrict__ bih1,
             const float* __restrict__ bhh1,
             float* __restrict__ h1s,
             float* __restrict__ outTail,
             unsigned* __restrict__ h0seq,
             float* __restrict__ z1ring,
             unsigned* __restrict__ flags) {
    // B0/B2: double-buffered record at lds[P*112 .. P*112+55]. Bz: 16 records.
    __shared__ __align__(16) unsigned lds[16 * 56];
    const int j = threadIdx.x;
    const int q = (j >> 1) & 3, u = j >> 3, H = j & 1;
    const int hoff = H * 112;                       // byte offset of my half in a record
    const int hidx = (u < 50) ? u : 56 + (u - 50);  // f16 index of h[u] in padded record
    const int kk = j - 832;
    const int pidx = (kk < 25) ? kk : kk + 3;       // u32 index of packed pair kk
    const float s_ = (q == 2) ? 2.f : 1.f;          // lane q==2: tanh = 2*sig(2x)-1
    const float addc_ = (q == 2) ? -1.f : 0.f;

    if (blockIdx.x == 0) {
        // ---------------- B0: layer-0 scan ----------------
        h2 w[25];
        float xa = 0.f, xb = 0.f, c0 = 0.f;
        if (j < 800) {
            int r = q * 100 + u;
            ldw(w, Whh0 + r * 100 + 50 * H);
            xa = (float)x0p[j >> 1];          // x(0), permuted layout
            xb = (float)x0p[400 + (j >> 1)];  // x(1)
        }
        if (j < 224) lds[j] = 0u;  // h0(-1)=0, both buffers
        __syncthreads();

        for (int t = 0; t < T_STEPS; t += 2) {
            B0TICK(t, xa, 0);
            B0TICK(t + 1, xb, 1);
        }
        if (j >= 832) {  // publish h0(T-1) (sits in buffer 0) + final flag
            if (kk < 50) AST(&h0seq[(size_t)(T_STEPS - 1) * 50 + kk], lds[pidx]);
            if (kk == 0) ASTR(&flags[0], (unsigned)T_STEPS);
        }
    } else if (blockIdx.x == 1) {
        // ---------------- Bz: z1 streaming GEMM, 16-tick tiles ----------------
        h2 w[25];
        float bz = 0.f;
        if (j < 800) {
            int r = q * 100 + u;
            ldw(w, Wih1 + r * 100 + 50 * H);
            bz = bih1[r] + bhh1[r];
        }
        for (int idx = j; idx < 16 * 56; idx += 896) lds[idx] = 0u;
        __syncthreads();

        unsigned fcache = 0, bpc = 0;
        for (int tau = 0; tau < 2048; ++tau) {
            const int t0 = tau * 16;
            // h0 availability: flags[0]=T means h0seq ticks <= T-1 done; need t0+15
            while (fcache < (unsigned)(t0 + 16)) {
                fcache = ALD(&flags[0]);
                if (fcache < (unsigned)(t0 + 16)) __builtin_amdgcn_s_sleep(8);
            }
            // ring backpressure (round-7 corruption fix): B2 must be within
            // 16384-32 ticks of the slots we are about to overwrite.
            int lim = t0 + 32 - (RMASK + 1);
            if (lim > 0) {
                while ((int)bpc < lim) {
                    bpc = ALD(&flags[2]);
                    if ((int)bpc < lim) __builtin_amdgcn_s_sleep(8);
                }
            }
            CFENCE();
            // stage tile: 800 packed u32 -> 16 padded LDS records
            if (j < 800) {
                int tt = j / 50, k = j % 50;
                lds[tt * 56 + ((k < 25) ? k : k + 3)] = ALD(&h0seq[(size_t)t0 * 50 + j]);
            }
            __syncthreads();
            if (j < 800) {
                for (int tt = 0; tt < 16; ++tt) {
                    float s_v = mv25s(w, (const char*)(lds + tt * 56) + hoff);
                    s_v += qperm<0xB1>(s_v);
                    if (H == 0)
                        AST(&z1ring[(size_t)((t0 + tt) & RMASK) * 400 + (j >> 1)], s_v + bz);
                }
            }
            __syncthreads();  // per-wave vmcnt(0) drain -> all z stores complete
            if (j == 0) ASTR(&flags[1], (unsigned)(tau + 1));
        }
    } else {
        // ---------------- B2: layer-1 scan ----------------
        h2 w[25];
        float za = 0.f, zb = 0.f, c1 = 0.f;
        unsigned zdc = 0;
        if (j < 800) {
            int r = q * 100 + u;
            ldw(w, Whh1 + r * 100 + 50 * H);
        }
        if (j < 224) lds[j] = 0u;  // h1(-1)=0, both buffers
        __syncthreads();
        if (j == 832) {  // wait for z tile 0 (ticks 0..15)
            while ((zdc = ALD(&flags[1])) < 1u) __builtin_amdgcn_s_sleep(8);
            CFENCE();
        }
        __syncthreads();
        if (j < 800) {
            za = ALD(&z1ring[j >> 1]);          // z(0)
            zb = ALD(&z1ring[400 + (j >> 1)]);  // z(1)
        }

        for (int t = 0; t < T_STEPS; t += 2) {
            B2TICK(t, za, 0);      // use z(t); prefetch za=z(t+2)
            B2TICK(t + 1, zb, 1);  // use z(t+1); prefetch zb=z(t+3)
        }
    }
}

// ---------------- C: outputs[t][d] = h1s[t] . W_out[d] + b_out[d] ----------------
__global__ __launch_bounds__(320) void k_out(const float* __restrict__ h1s,
                                             const float* __restrict__ Wout,
                                             const float* __restrict__ bout,
                                             float* __restrict__ out) {
    __shared__ float hs[32 * 100];
    int t0 = blockIdx.x * 32;
    for (int idx = threadIdx.x; idx < 3200; idx += 320) hs[idx] = h1s[(size_t)t0 * 100 + idx];
    __syncthreads();
    int d = threadIdx.x;
    if (d < 300) {
        float acc[32];
#pragma unroll
        for (int i = 0; i < 32; i++) acc[i] = 0.f;
        const float4* w4 = (const float4*)(Wout + d * 100);
        const float4* h4 = (const float4*)hs;
        for (int j4 = 0; j4 < 25; j4++) {
            float4 w = w4[j4];
#pragma unroll
            for (int ti = 0; ti < 32; ti++) {
                float4 h = h4[ti * 25 + j4];
                acc[ti] += w.x * h.x + w.y * h.y + w.z * h.z + w.w * h.w;
            }
        }
        float bb = bout[d];
#pragma unroll
        for (int ti = 0; ti < 32; ti++) out[(size_t)(t0 + ti) * 300 + d] = acc[ti] + bb;
    }
}

extern "C" void kernel_launch(void* const* d_in, const int* in_sizes, int n_in,
                              void* d_out, int out_size, void* d_ws, size_t ws_size,
                              hipStream_t stream) {
    const float* inputs = (const float*)d_in[0];
    const float* W_inp  = (const float*)d_in[1];
    const float* b_inp  = (const float*)d_in[2];
    const float* W_ih0  = (const float*)d_in[3];
    const float* W_hh0  = (const float*)d_in[4];
    const float* b_ih0  = (const float*)d_in[5];
    const float* b_hh0  = (const float*)d_in[6];
    const float* W_ih1  = (const float*)d_in[7];
    const float* W_hh1  = (const float*)d_in[8];
    const float* b_ih1  = (const float*)d_in[9];
    const float* b_hh1  = (const float*)d_in[10];
    const float* W_out  = (const float*)d_in[11];
    const float* b_out  = (const float*)d_in[12];
    float* out = (float*)d_out;

    char* ws = (char*)d_ws;
    _Float16* x0p = (_Float16*)ws;                    // 32768*400*2 = 26,214,400 B
    float* h1s = (float*)(ws + 26214400);             // 32768*100*4 = 13,107,200 B
    float* Wc  = (float*)(ws + 26214400 + 13107200);  // 400*300*4   =    480,000 B
    float* bc  = Wc + 120000;                         // 400*4 B

    // out-scratch region [0, OUT_BASE*4): fully overwritten by k_out afterwards.
    //   z1ring: 16384*400*4 = 26,214,400 B  @ 0
    //   h0seq : 32768*50*4  =  6,553,600 B  @ 26,214,400
    //   flags : 3 u32                       @ 32,768,000   (all < 39,321,600)
    float*    z1ring = out;
    unsigned* h0seq  = (unsigned*)((char*)out + 26214400);
    unsigned* flagsp = (unsigned*)((char*)out + 32768000);
    float*    outTail = out + OUT_BASE;

    hipMemsetAsync(flagsp, 0, 16, stream);
    k_precomp<<<471, 256, 0, stream>>>(W_inp, b_inp, W_ih0, b_ih0, b_hh0, Wc, bc);
    k_xproj<<<1024, 512, 0, stream>>>(inputs, Wc, bc, x0p);

    void* args[] = {(void*)&x0p, (void*)&W_hh0, (void*)&W_ih1, (void*)&W_hh1,
                    (void*)&b_ih1, (void*)&b_hh1, (void*)&h1s, (void*)&outTail,
                    (void*)&h0seq, (void*)&z1ring, (void*)&flagsp};
    hipLaunchCooperativeKernel((void*)k_scan3, dim3(3), dim3(896), args, 0, stream);

    k_out<<<1024, 320, 0, stream>>>(h1s, W_out, b_out, out);
}